// Round 7
// baseline (738.289 us; speedup 1.0000x reference)
//
#include <hip/hip_runtime.h>
#include <hip/hip_bf16.h>
#include <stdint.h>

// Problem constants
#define B_ROWS 131072
#define DD 256
#define KEXP 8
#define HH 128
#define BM 128        // rows per workgroup
#define NW 8          // waves per workgroup

typedef float  f32x4  __attribute__((ext_vector_type(4)));
typedef short  bf16x8 __attribute__((ext_vector_type(8)));

__device__ __forceinline__ unsigned short f2bf(float f) {
    uint32_t u = __builtin_bit_cast(uint32_t, f);
    u += 0x7fffu + ((u >> 16) & 1u);   // RTNE
    return (unsigned short)(u >> 16);
}

// exact-erf GELU via Abramowitz-Stegun 7.1.26 (|erf err| <= 1.5e-7)
__device__ __forceinline__ float gelu_erf(float x) {
    float s = x * 0.70710678118654752f;
    float a = fabsf(s);
    float t = __builtin_amdgcn_rcpf(fmaf(0.3275911f, a, 1.0f));
    float p = fmaf(t, 1.061405429f, -1.453152027f);
    p = fmaf(t, p, 1.421413741f);
    p = fmaf(t, p, -0.284496736f);
    p = fmaf(t, p, 0.254829592f);
    float e = __expf(-a * a);
    float Q = p * t * e;                        // = 1 - erf(a)
    float sel = (s >= 0.f) ? (2.0f - Q) : Q;    // 1 + erf(s)
    return 0.5f * x * sel;
}

__device__ __forceinline__ bf16x8 gelu_pack(f32x4 lo, f32x4 hi) {
    bf16x8 r;
    r[0] = f2bf(gelu_erf(lo[0])); r[1] = f2bf(gelu_erf(lo[1]));
    r[2] = f2bf(gelu_erf(lo[2])); r[3] = f2bf(gelu_erf(lo[3]));
    r[4] = f2bf(gelu_erf(hi[0])); r[5] = f2bf(gelu_erf(hi[1]));
    r[6] = f2bf(gelu_erf(hi[2])); r[7] = f2bf(gelu_erf(hi[3]));
    return r;
}

// Preconvert (weights consumed straight from L2 now — no LDS, no XOR swizzle):
//   W1 -> bf16 [k][h-row][32 chunks][8],  chunk sc holds d = sc*8+j  (linear)
//   W2 -> bf16 [k][g-row][16 chunks][8],  k-axis permuted by pi: h_bit4 <- k_bit2,
//         h_bit3 <- k_bit4, h_bit2 <- k_bit3 (3-cycle on bits {2,3,4}), so layer-1
//         C/D fragments (gelu'd, packed pairwise) feed layer-2's B operand directly.
__global__ void convert_weights(const float* __restrict__ W1, const float* __restrict__ W2,
                                uint16_t* __restrict__ w1o, uint16_t* __restrict__ w2o) {
    int idx = blockIdx.x * blockDim.x + threadIdx.x;
    const int total1 = KEXP * HH * DD;           // 262144
    if (idx < total1) {
        int k   = idx >> 15;
        int rem = idx & 32767;
        int h   = rem >> 8;
        int d   = rem & 255;
        w1o[idx] = f2bf(W1[(k * DD + d) * HH + h]);
        return;
    }
    int idx2 = idx - total1;
    const int total2 = KEXP * HH * HH;           // 131072
    if (idx2 < total2) {
        int k   = idx2 >> 14;
        int rem = idx2 & 16383;
        int gr  = rem >> 7;
        int kk  = rem & 127;                     // logical k position
        int h   = (kk & ~0x1C) | ((kk & 4) << 2) | ((kk & 0x18) >> 1);  // pi (3-cycle 2->4->3->2)
        w2o[idx2] = f2bf(W2[(k * HH + h) * HH + gr]);
    }
}

#define SBAR() __builtin_amdgcn_sched_barrier(0)

__global__ __launch_bounds__(512, 4)
void moe_kernel(const float* __restrict__ z, const float* __restrict__ probs,
                const float* __restrict__ b1, const float* __restrict__ b2,
                const float* __restrict__ W3, const float* __restrict__ b3,
                const uint16_t* __restrict__ w1g, const uint16_t* __restrict__ w2g,
                float* __restrict__ out) {
    // per-wave z tile, chunk-major: [32 chunks][16 rows][8 bf16] = 8 KB/wave.
    // Fragment read (fixed kk): 64 lanes read a contiguous 1 KB block -> conflict-free.
    __shared__ __align__(16) uint16_t z_lds[NW * 4096];   // 64 KB
    __shared__ __align__(16) float preds_lds[BM * KEXP];  // 4 KB

    const int tid  = threadIdx.x;
    const int wave = tid >> 6;
    const int lane = tid & 63;
    const int c    = lane & 15;
    const int g    = lane >> 4;
    const int wg   = blockIdx.x;
    const long rowbase = (long)wg * BM;

    // ---- stage z (f32 global -> bf16 LDS), wave-private, no block barrier needed ----
    {
        const float* zr = z + (rowbase + wave * 16 + c) * DD + g * 8;
        uint16_t* zl = z_lds + wave * 4096 + g * 128 + c * 8;
        #pragma unroll
        for (int i = 0; i < 8; ++i) {
            float4 x0 = *(const float4*)(zr + 32 * i);
            float4 x1 = *(const float4*)(zr + 32 * i + 4);
            bf16x8 f;
            f[0] = f2bf(x0.x); f[1] = f2bf(x0.y); f[2] = f2bf(x0.z); f[3] = f2bf(x0.w);
            f[4] = f2bf(x1.x); f[5] = f2bf(x1.y); f[6] = f2bf(x1.z); f[7] = f2bf(x1.w);
            *(bf16x8*)(zl + 512 * i) = f;       // chunk 4i+g, row c
        }
    }
    asm volatile("s_waitcnt lgkmcnt(0)" ::: "memory");
    SBAR();

    const uint16_t* zlr = z_lds + wave * 4096 + c * 8;    // + (4kk+g)*128 per fragment

    for (int ke = 0; ke < KEXP; ++ke) {
        bf16x8 pa0, pa1, pa2, pa3;
        const uint16_t* w1p = w1g + ke * (HH * DD) + c * DD;
        const float* bb1 = b1 + ke * HH;

        // ---- layer 1, h rows 0-63 (A-frags from global/L2) ----
        {
            f32x4 a0 = *(const f32x4*)(bb1 +  0 + 4 * g);
            f32x4 a1 = *(const f32x4*)(bb1 + 16 + 4 * g);
            f32x4 a2 = *(const f32x4*)(bb1 + 32 + 4 * g);
            f32x4 a3 = *(const f32x4*)(bb1 + 48 + 4 * g);
            SBAR();
            #pragma unroll
            for (int kk = 0; kk < 8; ++kk) {
                bf16x8 zfk = *(const bf16x8*)(zlr + (4 * kk + g) * 128);
                const uint16_t* base = w1p + (4 * kk + g) * 8;
                a0 = __builtin_amdgcn_mfma_f32_16x16x32_bf16(*(const bf16x8*)(base        ), zfk, a0, 0, 0, 0);
                a1 = __builtin_amdgcn_mfma_f32_16x16x32_bf16(*(const bf16x8*)(base +  4096), zfk, a1, 0, 0, 0);
                a2 = __builtin_amdgcn_mfma_f32_16x16x32_bf16(*(const bf16x8*)(base +  8192), zfk, a2, 0, 0, 0);
                a3 = __builtin_amdgcn_mfma_f32_16x16x32_bf16(*(const bf16x8*)(base + 12288), zfk, a3, 0, 0, 0);
                if (kk & 1) SBAR();
            }
            pa0 = gelu_pack(a0, a1);   // h rows 0-31 (pi-packed)
            pa1 = gelu_pack(a2, a3);   // h rows 32-63
        }

        // ---- layer 1, h rows 64-127 ----
        {
            f32x4 a0 = *(const f32x4*)(bb1 +  64 + 4 * g);
            f32x4 a1 = *(const f32x4*)(bb1 +  80 + 4 * g);
            f32x4 a2 = *(const f32x4*)(bb1 +  96 + 4 * g);
            f32x4 a3 = *(const f32x4*)(bb1 + 112 + 4 * g);
            SBAR();
            const uint16_t* w1q = w1p + 64 * DD;
            #pragma unroll
            for (int kk = 0; kk < 8; ++kk) {
                bf16x8 zfk = *(const bf16x8*)(zlr + (4 * kk + g) * 128);
                const uint16_t* base = w1q + (4 * kk + g) * 8;
                a0 = __builtin_amdgcn_mfma_f32_16x16x32_bf16(*(const bf16x8*)(base        ), zfk, a0, 0, 0, 0);
                a1 = __builtin_amdgcn_mfma_f32_16x16x32_bf16(*(const bf16x8*)(base +  4096), zfk, a1, 0, 0, 0);
                a2 = __builtin_amdgcn_mfma_f32_16x16x32_bf16(*(const bf16x8*)(base +  8192), zfk, a2, 0, 0, 0);
                a3 = __builtin_amdgcn_mfma_f32_16x16x32_bf16(*(const bf16x8*)(base + 12288), zfk, a3, 0, 0, 0);
                if (kk & 1) SBAR();
            }
            pa2 = gelu_pack(a0, a1);   // h rows 64-95
            pa3 = gelu_pack(a2, a3);   // h rows 96-127
        }

        // ---- layer 2 (W2 A-frags from global/L2; pa as B operand via pi) ----
        {
            const float* bb2 = b2 + ke * HH;
            f32x4 q0 = *(const f32x4*)(bb2 +   0 + 4 * g);
            f32x4 q1 = *(const f32x4*)(bb2 +  16 + 4 * g);
            SBAR();
            f32x4 q2 = *(const f32x4*)(bb2 +  32 + 4 * g);
            f32x4 q3 = *(const f32x4*)(bb2 +  48 + 4 * g);
            SBAR();
            f32x4 q4 = *(const f32x4*)(bb2 +  64 + 4 * g);
            f32x4 q5 = *(const f32x4*)(bb2 +  80 + 4 * g);
            SBAR();
            f32x4 q6 = *(const f32x4*)(bb2 +  96 + 4 * g);
            f32x4 q7 = *(const f32x4*)(bb2 + 112 + 4 * g);
            SBAR();
            const uint16_t* w2p = w2g + ke * (HH * HH) + c * HH;
            #pragma unroll
            for (int kk2 = 0; kk2 < 4; ++kk2) {
                bf16x8 pa = (kk2 == 0) ? pa0 : (kk2 == 1) ? pa1 : (kk2 == 2) ? pa2 : pa3;
                const uint16_t* base = w2p + (4 * kk2 + g) * 8;
                q0 = __builtin_amdgcn_mfma_f32_16x16x32_bf16(*(const bf16x8*)(base        ), pa, q0, 0, 0, 0);
                q1 = __builtin_amdgcn_mfma_f32_16x16x32_bf16(*(const bf16x8*)(base +  2048), pa, q1, 0, 0, 0);
                q2 = __builtin_amdgcn_mfma_f32_16x16x32_bf16(*(const bf16x8*)(base +  4096), pa, q2, 0, 0, 0);
                q3 = __builtin_amdgcn_mfma_f32_16x16x32_bf16(*(const bf16x8*)(base +  6144), pa, q3, 0, 0, 0);
                q4 = __builtin_amdgcn_mfma_f32_16x16x32_bf16(*(const bf16x8*)(base +  8192), pa, q4, 0, 0, 0);
                q5 = __builtin_amdgcn_mfma_f32_16x16x32_bf16(*(const bf16x8*)(base + 10240), pa, q5, 0, 0, 0);
                q6 = __builtin_amdgcn_mfma_f32_16x16x32_bf16(*(const bf16x8*)(base + 12288), pa, q6, 0, 0, 0);
                q7 = __builtin_amdgcn_mfma_f32_16x16x32_bf16(*(const bf16x8*)(base + 14336), pa, q7, 0, 0, 0);
                SBAR();
            }

            // GELU + layer-3 dot: lane holds g2 = 16*hb2 + 4g + r, m = c
            const float* w3p = W3 + ke * HH;
            float part = 0.f;
            f32x4 w3v;
            #define DOT(qq, off) \
                w3v = *(const f32x4*)(w3p + off + 4 * g); \
                part = fmaf(gelu_erf(qq[0]), w3v[0], part); \
                part = fmaf(gelu_erf(qq[1]), w3v[1], part); \
                part = fmaf(gelu_erf(qq[2]), w3v[2], part); \
                part = fmaf(gelu_erf(qq[3]), w3v[3], part);
            DOT(q0,   0) DOT(q1,  16) SBAR();
            DOT(q2,  32) DOT(q3,  48) SBAR();
            DOT(q4,  64) DOT(q5,  80) SBAR();
            DOT(q6,  96) DOT(q7, 112) SBAR();
            #undef DOT
            part += __shfl_xor(part, 16);
            part += __shfl_xor(part, 32);
            if (g == 0)
                preds_lds[(wave * 16 + c) * KEXP + ke] = part + b3[ke];
        }
    }

    __syncthreads();   // preds_lds complete across waves

    // expert_preds: coalesced 1024 f32 per WG
    {
        float2 v = *(const float2*)(preds_lds + tid * 2);
        *(float2*)(out + B_ROWS + rowbase * KEXP + tid * 2) = v;
    }
    // blended: 128 f32 per WG (probs straight from global, coalesced)
    if (tid < BM) {
        const float* pr = probs + (rowbase + tid) * KEXP;
        float4 p0 = *(const float4*)(pr);
        float4 p1 = *(const float4*)(pr + 4);
        const float* pd = preds_lds + tid * KEXP;
        float s = 0.f;
        s = fmaf(p0.x, pd[0], s); s = fmaf(p0.y, pd[1], s);
        s = fmaf(p0.z, pd[2], s); s = fmaf(p0.w, pd[3], s);
        s = fmaf(p1.x, pd[4], s); s = fmaf(p1.y, pd[5], s);
        s = fmaf(p1.z, pd[6], s); s = fmaf(p1.w, pd[7], s);
        out[rowbase + tid] = s;
    }
}

extern "C" void kernel_launch(void* const* d_in, const int* in_sizes, int n_in,
                              void* d_out, int out_size, void* d_ws, size_t ws_size,
                              hipStream_t stream) {
    const float* z     = (const float*)d_in[0];
    const float* probs = (const float*)d_in[1];
    const float* W1    = (const float*)d_in[2];
    const float* b1    = (const float*)d_in[3];
    const float* W2    = (const float*)d_in[4];
    const float* b2    = (const float*)d_in[5];
    const float* W3    = (const float*)d_in[6];
    const float* b3    = (const float*)d_in[7];
    float* out = (float*)d_out;

    uint16_t* w1b = (uint16_t*)d_ws;                       // 8*128*256 bf16 = 512 KB
    uint16_t* w2b = w1b + (size_t)KEXP * HH * DD;          // 8*128*128 bf16 = 256 KB

    const int totalw = KEXP * HH * DD + KEXP * HH * HH;    // 393216
    convert_weights<<<(totalw + 255) / 256, 256, 0, stream>>>(W1, W2, w1b, w2b);
    moe_kernel<<<B_ROWS / BM, 512, 0, stream>>>(z, probs, b1, b2, W3, b3, w1b, w2b, out);
}

// Round 8
// 232.075 us; speedup vs baseline: 3.1813x; 3.1813x over previous
//
#include <hip/hip_runtime.h>
#include <hip/hip_bf16.h>
#include <stdint.h>

// Problem constants
#define B_ROWS 131072
#define DD 256
#define KEXP 8
#define HH 128
#define BM 64         // rows per workgroup (4 waves x 16 rows)
#define NW 4          // waves per workgroup

typedef float  f32x4  __attribute__((ext_vector_type(4)));
typedef short  bf16x8 __attribute__((ext_vector_type(8)));

__device__ __forceinline__ unsigned short f2bf(float f) {
    uint32_t u = __builtin_bit_cast(uint32_t, f);
    u += 0x7fffu + ((u >> 16) & 1u);   // RTNE
    return (unsigned short)(u >> 16);
}

// exact-erf GELU via Abramowitz-Stegun 7.1.26 (|erf err| <= 1.5e-7)
__device__ __forceinline__ float gelu_erf(float x) {
    float s = x * 0.70710678118654752f;
    float a = fabsf(s);
    float t = __builtin_amdgcn_rcpf(fmaf(0.3275911f, a, 1.0f));
    float p = fmaf(t, 1.061405429f, -1.453152027f);
    p = fmaf(t, p, 1.421413741f);
    p = fmaf(t, p, -0.284496736f);
    p = fmaf(t, p, 0.254829592f);
    float e = __expf(-a * a);
    float Q = p * t * e;                        // = 1 - erf(a)
    float sel = (s >= 0.f) ? (2.0f - Q) : Q;    // 1 + erf(s)
    return 0.5f * x * sel;
}

__device__ __forceinline__ bf16x8 gelu_pack(f32x4 lo, f32x4 hi) {
    bf16x8 r;
    r[0] = f2bf(gelu_erf(lo[0])); r[1] = f2bf(gelu_erf(lo[1]));
    r[2] = f2bf(gelu_erf(lo[2])); r[3] = f2bf(gelu_erf(lo[3]));
    r[4] = f2bf(gelu_erf(hi[0])); r[5] = f2bf(gelu_erf(hi[1]));
    r[6] = f2bf(gelu_erf(hi[2])); r[7] = f2bf(gelu_erf(hi[3]));
    return r;
}

// Preconvert (round-4 verified layout):
//   W1 -> bf16 [k][h-row][32 slots][8], slot sc holds d-chunk kc = sc ^ (h&7).
//   W2 -> bf16 [k][g-row][16 slots][8], slot sc holds h-chunk kc = sc ^ (gr&7),
//         k-axis permuted by pi: h_bit4 <- k_bit2, h_bit3 <- k_bit4, h_bit2 <- k_bit3
//         (3-cycle on bits {2,3,4}), so layer-1 C/D fragments (gelu'd, packed pairwise)
//         feed layer-2's B operand directly with no LDS round-trip.
__global__ void convert_weights(const float* __restrict__ W1, const float* __restrict__ W2,
                                uint16_t* __restrict__ w1o, uint16_t* __restrict__ w2o) {
    int idx = blockIdx.x * blockDim.x + threadIdx.x;
    const int total1 = KEXP * HH * DD;           // 262144
    if (idx < total1) {
        int k   = idx >> 15;
        int rem = idx & 32767;
        int h   = rem >> 8;
        int r2  = rem & 255;
        int sc  = r2 >> 3;                       // 0..31
        int j   = r2 & 7;
        int kc  = sc ^ (h & 7);
        int d   = kc * 8 + j;
        w1o[idx] = f2bf(W1[(k * DD + d) * HH + h]);
        return;
    }
    int idx2 = idx - total1;
    const int total2 = KEXP * HH * HH;           // 131072
    if (idx2 < total2) {
        int k   = idx2 >> 14;
        int rem = idx2 & 16383;
        int gr  = rem >> 7;
        int r2  = rem & 127;
        int sc  = r2 >> 3;                       // 0..15
        int j   = r2 & 7;
        int kk  = (sc ^ (gr & 7)) * 8 + j;       // logical k position
        int h   = (kk & ~0x1C) | ((kk & 4) << 2) | ((kk & 0x18) >> 1);  // pi (3-cycle 2->4->3->2)
        w2o[idx2] = f2bf(W2[(k * HH + h) * HH + gr]);
    }
}

// stage 16KB with 256 threads: 4 waves x 4 iters x (64 lanes x 16B).
// LDS dest is wave-uniform base + lane*16 (HW rule).
__device__ __forceinline__ void stage16k(const uint16_t* __restrict__ src, uint16_t* dst,
                                         int wave, int lane) {
    const char* s = (const char*)src + wave * 1024 + lane * 16;
    char* d = (char*)dst + wave * 1024;
    #pragma unroll
    for (int i = 0; i < 4; ++i)
        __builtin_amdgcn_global_load_lds(
            (const __attribute__((address_space(1))) void*)(s + i * 4096),
            (__attribute__((address_space(3))) void*)(d + i * 4096), 16, 0, 0);
}

__global__ __launch_bounds__(256, 3)
void moe_kernel(const float* __restrict__ z, const float* __restrict__ probs,
                const float* __restrict__ b1, const float* __restrict__ b2,
                const float* __restrict__ W3, const float* __restrict__ b3,
                const uint16_t* __restrict__ w1b, const uint16_t* __restrict__ w2b,
                float* __restrict__ out) {
    __shared__ __align__(16) uint16_t wbuf[2][8192];      // 2 x 16 KB ping-pong
    __shared__ __align__(16) float preds_lds[BM * KEXP];  // 2 KB

    const int tid  = threadIdx.x;
    const int wave = tid >> 6;
    const int lane = tid & 63;
    const int c    = lane & 15;
    const int g    = lane >> 4;
    const int wg   = blockIdx.x;
    const long rowbase = (long)wg * BM;

    // z fragments in registers: lane holds z[row = wave*16 + c][d = kk*32 + 8g + j]
    bf16x8 zf[8];
    {
        const float* zr = z + (rowbase + wave * 16 + c) * DD;
        #pragma unroll
        for (int kk = 0; kk < 8; ++kk) {
            const float* p = zr + kk * 32 + g * 8;
            float4 x0 = *(const float4*)(p);
            float4 x1 = *(const float4*)(p + 4);
            bf16x8 f;
            f[0] = f2bf(x0.x); f[1] = f2bf(x0.y); f[2] = f2bf(x0.z); f[3] = f2bf(x0.w);
            f[4] = f2bf(x1.x); f[5] = f2bf(x1.y); f[6] = f2bf(x1.z); f[7] = f2bf(x1.w);
            zf[kk] = f;
        }
    }

    // prologue: stage expert 0, W1 quarter 0
    stage16k(w1b, wbuf[0], wave, lane);
    __syncthreads();

    int cur = 0;
    const int cswz = c & 7;

    for (int ke = 0; ke < KEXP; ++ke) {
        bf16x8 pa[4];
        const uint16_t* w1e = w1b + ke * (HH * DD);
        const uint16_t* w2e = w2b + ke * (HH * HH);
        const float* bb1 = b1 + ke * HH;

        // ---- phases A-D: layer-1 quarter q (32 h-rows, 16KB); stage next buffer ----
        #pragma unroll
        for (int q = 0; q < 4; ++q) {
            // stage: q<3 -> W1 quarter q+1 ; q==3 -> W2 half 0
            if (q < 3) stage16k(w1e + (q + 1) * 8192, wbuf[cur ^ 1], wave, lane);
            else       stage16k(w2e,                  wbuf[cur ^ 1], wave, lane);

            f32x4 a0 = *(const f32x4*)(bb1 + 32 * q +  0 + 4 * g);
            f32x4 a1 = *(const f32x4*)(bb1 + 32 * q + 16 + 4 * g);
            const uint16_t* wb = wbuf[cur];
            #pragma unroll
            for (int kk = 0; kk < 8; ++kk) {
                int slot = (4 * kk + g) ^ cswz;
                const uint16_t* base = wb + c * 256 + slot * 8;
                a0 = __builtin_amdgcn_mfma_f32_16x16x32_bf16(*(const bf16x8*)(base       ), zf[kk], a0, 0, 0, 0);
                a1 = __builtin_amdgcn_mfma_f32_16x16x32_bf16(*(const bf16x8*)(base + 4096), zf[kk], a1, 0, 0, 0);
            }
            pa[q] = gelu_pack(a0, a1);   // h rows 32q..32q+31 (pi-packed)
            __syncthreads(); cur ^= 1;
        }

        // ---- phase E: layer-2 half 0 (g2 rows 0-63); stage W2 half 1 ----
        f32x4 q0, q1, q2, q3;
        {
            stage16k(w2e + 8192, wbuf[cur ^ 1], wave, lane);
            const float* bb2 = b2 + ke * HH;
            q0 = *(const f32x4*)(bb2 +  0 + 4 * g);
            q1 = *(const f32x4*)(bb2 + 16 + 4 * g);
            q2 = *(const f32x4*)(bb2 + 32 + 4 * g);
            q3 = *(const f32x4*)(bb2 + 48 + 4 * g);
            const uint16_t* wb = wbuf[cur];
            #pragma unroll
            for (int kk2 = 0; kk2 < 4; ++kk2) {
                int slot = (4 * kk2 + g) ^ cswz;
                const uint16_t* base = wb + c * 128 + slot * 8;
                q0 = __builtin_amdgcn_mfma_f32_16x16x32_bf16(*(const bf16x8*)(base       ), pa[kk2], q0, 0, 0, 0);
                q1 = __builtin_amdgcn_mfma_f32_16x16x32_bf16(*(const bf16x8*)(base + 2048), pa[kk2], q1, 0, 0, 0);
                q2 = __builtin_amdgcn_mfma_f32_16x16x32_bf16(*(const bf16x8*)(base + 4096), pa[kk2], q2, 0, 0, 0);
                q3 = __builtin_amdgcn_mfma_f32_16x16x32_bf16(*(const bf16x8*)(base + 6144), pa[kk2], q3, 0, 0, 0);
            }
            __syncthreads(); cur ^= 1;
        }

        // ---- phase F: layer-2 half 1 (g2 rows 64-127); stage next expert's Q0; dot ----
        {
            if (ke + 1 < KEXP) stage16k(w1b + (ke + 1) * (HH * DD), wbuf[cur ^ 1], wave, lane);
            const float* bb2 = b2 + ke * HH + 64;
            f32x4 q4 = *(const f32x4*)(bb2 +  0 + 4 * g);
            f32x4 q5 = *(const f32x4*)(bb2 + 16 + 4 * g);
            f32x4 q6 = *(const f32x4*)(bb2 + 32 + 4 * g);
            f32x4 q7 = *(const f32x4*)(bb2 + 48 + 4 * g);
            const uint16_t* wb = wbuf[cur];
            #pragma unroll
            for (int kk2 = 0; kk2 < 4; ++kk2) {
                int slot = (4 * kk2 + g) ^ cswz;
                const uint16_t* base = wb + c * 128 + slot * 8;
                q4 = __builtin_amdgcn_mfma_f32_16x16x32_bf16(*(const bf16x8*)(base       ), pa[kk2], q4, 0, 0, 0);
                q5 = __builtin_amdgcn_mfma_f32_16x16x32_bf16(*(const bf16x8*)(base + 2048), pa[kk2], q5, 0, 0, 0);
                q6 = __builtin_amdgcn_mfma_f32_16x16x32_bf16(*(const bf16x8*)(base + 4096), pa[kk2], q6, 0, 0, 0);
                q7 = __builtin_amdgcn_mfma_f32_16x16x32_bf16(*(const bf16x8*)(base + 6144), pa[kk2], q7, 0, 0, 0);
            }

            // GELU + layer-3 dot: lane holds g2 = 16*hb2 + 4g + r, m = c
            const float* w3p = W3 + ke * HH;
            float part = 0.f;
            f32x4 w3v;
            #define DOT(qq, off) \
                w3v = *(const f32x4*)(w3p + off + 4 * g); \
                part = fmaf(gelu_erf(qq[0]), w3v[0], part); \
                part = fmaf(gelu_erf(qq[1]), w3v[1], part); \
                part = fmaf(gelu_erf(qq[2]), w3v[2], part); \
                part = fmaf(gelu_erf(qq[3]), w3v[3], part);
            DOT(q0,   0) DOT(q1,  16) DOT(q2,  32) DOT(q3,  48)
            DOT(q4,  64) DOT(q5,  80) DOT(q6,  96) DOT(q7, 112)
            #undef DOT
            part += __shfl_xor(part, 16);
            part += __shfl_xor(part, 32);
            if (g == 0)
                preds_lds[(wave * 16 + c) * KEXP + ke] = part + b3[ke];
            __syncthreads(); cur ^= 1;
        }
    }

    // expert_preds: coalesced 512 f32 per WG
    {
        float2 v = *(const float2*)(preds_lds + tid * 2);
        *(float2*)(out + B_ROWS + rowbase * KEXP + tid * 2) = v;
    }
    // blended: 64 f32 per WG (probs straight from global, coalesced)
    if (tid < BM) {
        const float* pr = probs + (rowbase + tid) * KEXP;
        float4 p0 = *(const float4*)(pr);
        float4 p1 = *(const float4*)(pr + 4);
        const float* pd = preds_lds + tid * KEXP;
        float s = 0.f;
        s = fmaf(p0.x, pd[0], s); s = fmaf(p0.y, pd[1], s);
        s = fmaf(p0.z, pd[2], s); s = fmaf(p0.w, pd[3], s);
        s = fmaf(p1.x, pd[4], s); s = fmaf(p1.y, pd[5], s);
        s = fmaf(p1.z, pd[6], s); s = fmaf(p1.w, pd[7], s);
        out[rowbase + tid] = s;
    }
}

extern "C" void kernel_launch(void* const* d_in, const int* in_sizes, int n_in,
                              void* d_out, int out_size, void* d_ws, size_t ws_size,
                              hipStream_t stream) {
    const float* z     = (const float*)d_in[0];
    const float* probs = (const float*)d_in[1];
    const float* W1    = (const float*)d_in[2];
    const float* b1    = (const float*)d_in[3];
    const float* W2    = (const float*)d_in[4];
    const float* b2    = (const float*)d_in[5];
    const float* W3    = (const float*)d_in[6];
    const float* b3    = (const float*)d_in[7];
    float* out = (float*)d_out;

    uint16_t* w1b = (uint16_t*)d_ws;                       // 8*128*256 bf16 = 512 KB
    uint16_t* w2b = w1b + (size_t)KEXP * HH * DD;          // 8*128*128 bf16 = 256 KB

    const int totalw = KEXP * HH * DD + KEXP * HH * HH;    // 393216
    convert_weights<<<(totalw + 255) / 256, 256, 0, stream>>>(W1, W2, w1b, w2b);
    moe_kernel<<<B_ROWS / BM, 256, 0, stream>>>(z, probs, b1, b2, W3, b3, w1b, w2b, out);
}